// Round 1
// 302.096 us; speedup vs baseline: 1.0860x; 1.0860x over previous
//
#include <hip/hip_runtime.h>
#include <hip/hip_fp16.h>

#define CIN   64
#define COUT  64

typedef __attribute__((ext_vector_type(8))) short bf16x8;
typedef __attribute__((ext_vector_type(4))) float f32x4;

// round-to-nearest-even f32 -> bf16 (bit pattern as ushort)
__device__ inline unsigned short f2bf(float f) {
    unsigned u = __float_as_uint(f);
    return (unsigned short)((u + 0x7FFFu + ((u >> 16) & 1u)) >> 16);
}

__device__ inline unsigned pack_h2(float lo, float hi) {
    __half l = __float2half(lo), h = __float2half(hi);
    return (unsigned)__half_as_ushort(l) | ((unsigned)__half_as_ushort(h) << 16);
}

__device__ inline float2 h2f2(unsigned v) {
    return make_float2(
        __half2float(__ushort_as_half((unsigned short)(v & 0xFFFFu))),
        __half2float(__ushort_as_half((unsigned short)(v >> 16))));
}

// ---------------------------------------------------------------------------
// Fused: feats fp32 -> bf16 AND out_map histogram; ALSO records each pair's
// rank within its output row (the atomic's return value). This rank replaces
// phase1's slot atomic entirely: slot = offsets[out_row] + rank.
// cnt must be pre-zeroed.
// ---------------------------------------------------------------------------
__global__ __launch_bounds__(256)
void cvt_hist(const float4* __restrict__ in, unsigned short* __restrict__ outb,
              int n8, const int* __restrict__ out_map, int total,
              int* __restrict__ cnt, int* __restrict__ rk) {
    int i = blockIdx.x * 256 + threadIdx.x;
    if (i < n8) {
        float4 f0 = in[2 * i], f1 = in[2 * i + 1];
        bf16x8 o;
        o[0] = (short)f2bf(f0.x); o[1] = (short)f2bf(f0.y);
        o[2] = (short)f2bf(f0.z); o[3] = (short)f2bf(f0.w);
        o[4] = (short)f2bf(f1.x); o[5] = (short)f2bf(f1.y);
        o[6] = (short)f2bf(f1.z); o[7] = (short)f2bf(f1.w);
        *(bf16x8*)(outb + 8 * (size_t)i) = o;
    }
    if (i < total)
        rk[i] = atomicAdd(&cnt[out_map[i]], 1);
}

// CSR build 2a: per-block (1024 elems) exclusive scan + block sums.
__global__ __launch_bounds__(256)
void scanA(const int* __restrict__ cnt, int* __restrict__ excl,
           int* __restrict__ blocksum, int N) {
    __shared__ int sm[256];
    const int b = blockIdx.x, t = threadIdx.x;
    const int base = b * 1024 + t * 4;
    int v0 = (base + 0 < N) ? cnt[base + 0] : 0;
    int v1 = (base + 1 < N) ? cnt[base + 1] : 0;
    int v2 = (base + 2 < N) ? cnt[base + 2] : 0;
    int v3 = (base + 3 < N) ? cnt[base + 3] : 0;
    const int s = v0 + v1 + v2 + v3;
    sm[t] = s; __syncthreads();
    for (int off = 1; off < 256; off <<= 1) {
        int x = (t >= off) ? sm[t - off] : 0;
        __syncthreads();
        sm[t] += x;
        __syncthreads();
    }
    const int e = sm[t] - s;
    if (t == 255) blocksum[b] = sm[t];
    if (base + 0 < N) excl[base + 0] = e;
    if (base + 1 < N) excl[base + 1] = e + v0;
    if (base + 2 < N) excl[base + 2] = e + v0 + v1;
    if (base + 3 < N) excl[base + 3] = e + v0 + v1 + v2;
}

// CSR build 2b: scan block sums (nb <= 256), write grand total at offsets[N].
__global__ __launch_bounds__(256)
void scanB(const int* __restrict__ blocksum, int* __restrict__ blockbase,
           int nb, int* __restrict__ total_out) {
    __shared__ int sm[256];
    const int t = threadIdx.x;
    const int s = (t < nb) ? blocksum[t] : 0;
    sm[t] = s; __syncthreads();
    for (int off = 1; off < 256; off <<= 1) {
        int x = (t >= off) ? sm[t - off] : 0;
        __syncthreads();
        sm[t] += x;
        __syncthreads();
    }
    if (t < nb) blockbase[t] = sm[t] - s;
    if (t == 255) *total_out = sm[255];
}

// CSR build 2c: add block bases (no duplicate array needed anymore — phase1
// reads offsets read-only).
__global__ __launch_bounds__(256)
void scanC(int* __restrict__ offsets, const int* __restrict__ blockbase, int N) {
    int i = blockIdx.x * 256 + threadIdx.x;
    if (i >= N) return;
    offsets[i] += blockbase[i >> 10];
}

// ---------------------------------------------------------------------------
// Phase 1: implicit-GEMM (MFMA), DEPTH-3 software pipeline:
//   S0: coalesced map+rank loads          (tile t+2)
//   S1: offsets gather + feats gather     (tile t+1)
//   S2: MFMA + epilogue + partial stores  (tile t)
// Every memory op gets >= 1 full iteration of slack; no load depends on a
// same-iteration load; NO atomics (slot = offsets[out_row] + rank).
// ---------------------------------------------------------------------------
__global__ __launch_bounds__(256)
void spconv_phase1(const unsigned short* __restrict__ featsb,
                   const float*          __restrict__ weight,
                   const int*            __restrict__ in_map,
                   const int*            __restrict__ out_map,
                   const int*            __restrict__ offsets,
                   const int*            __restrict__ rk,
                   unsigned*             __restrict__ partial_dw,
                   int M) {
    const int k      = blockIdx.y;
    const int tid    = threadIdx.x;
    const int lane   = tid & 63;
    const int m      = lane & 15;
    const int quad   = lane >> 4;
    const int wave   = blockIdx.x * 4 + (tid >> 6);
    const int nwaves = gridDim.x * 4;
    const bool odd   = (m & 1);

    // Preload B fragments: b[t][h][j] = W[k][32h+8q+j][16t+m]
    const float* __restrict__ wk = weight + (size_t)k * (CIN * COUT);
    bf16x8 bfrag[4][2];
#pragma unroll
    for (int t = 0; t < 4; ++t)
#pragma unroll
        for (int h = 0; h < 2; ++h) {
            const int n  = 16 * t + m;
            const int c0 = 32 * h + 8 * quad;
#pragma unroll
            for (int j = 0; j < 8; ++j)
                bfrag[t][h][j] = (short)f2bf(wk[(c0 + j) * COUT + n]);
        }

    const int base   = k * M;
    const int ntiles = M >> 4;   // 3125

    int t0 = wave, t1 = wave + nwaves, t2 = wave + 2 * nwaves;

    // ---- prologue ----
    // S0(t0)
    int ir0 = 0, orow0 = 0, rk0 = 0;
    if (t0 < ntiles) {
        const int p = base + (t0 << 4) + m;
        ir0 = in_map[p]; orow0 = out_map[p]; rk0 = rk[p];
    }
    // S1(t0)
    int slt0 = 0; bf16x8 a0_0 = {}, a1_0 = {};
    if (t0 < ntiles) {
        if (quad == 0) slt0 = offsets[orow0] + rk0;
        const unsigned short* fb = featsb + ((size_t)ir0 << 6) + 8 * quad;
        a0_0 = *(const bf16x8*)fb;
        a1_0 = *(const bf16x8*)(fb + 32);
    }
    // S0(t1)
    int ir1 = 0, orow1 = 0, rk1 = 0;
    if (t1 < ntiles) {
        const int p = base + (t1 << 4) + m;
        ir1 = in_map[p]; orow1 = out_map[p]; rk1 = rk[p];
    }

    while (t0 < ntiles) {
        // ---- S1(t1): slot lookup + feats gather ----
        int slt1 = 0; bf16x8 a0_1 = {}, a1_1 = {};
        if (t1 < ntiles) {
            if (quad == 0) slt1 = offsets[orow1] + rk1;
            const unsigned short* fb = featsb + ((size_t)ir1 << 6) + 8 * quad;
            a0_1 = *(const bf16x8*)fb;
            a1_1 = *(const bf16x8*)(fb + 32);
        }
        // ---- S0(t2): coalesced map + rank loads ----
        int ir2 = 0, orow2 = 0, rk2 = 0;
        if (t2 < ntiles) {
            const int p = base + (t2 << 4) + m;
            ir2 = in_map[p]; orow2 = out_map[p]; rk2 = rk[p];
        }

        // ---- S2(t0): MFMA ----
        f32x4 acc[4];
#pragma unroll
        for (int t = 0; t < 4; ++t) {
            acc[t] = {0.f, 0.f, 0.f, 0.f};
            acc[t] = __builtin_amdgcn_mfma_f32_16x16x32_bf16(a0_0, bfrag[t][0], acc[t], 0, 0, 0);
            acc[t] = __builtin_amdgcn_mfma_f32_16x16x32_bf16(a1_0, bfrag[t][1], acc[t], 0, 0, 0);
        }

        // Epilogue: pair cols (m, m^1) via shfl_xor(1); even lane writes
        // C-rows 4q+{0,1}, odd lane 4q+{2,3}; dword half2 stores at CSR slots.
        const int row0  = 4 * quad + (odd ? 2 : 0);
        const int s0    = __shfl(slt0, row0);     // quad-0 lane row0 holds it
        const int s1    = __shfl(slt0, row0 + 1);
        const int coldw = m >> 1;
#pragma unroll
        for (int t = 0; t < 4; ++t) {
            const float send0 = odd ? acc[t][0] : acc[t][2];
            const float send1 = odd ? acc[t][1] : acc[t][3];
            const float recv0 = __shfl_xor(send0, 1);
            const float recv1 = __shfl_xor(send1, 1);

            const unsigned d0 = odd ? pack_h2(recv0, acc[t][2])
                                    : pack_h2(acc[t][0], recv0);
            const unsigned d1 = odd ? pack_h2(recv1, acc[t][3])
                                    : pack_h2(acc[t][1], recv1);

            partial_dw[(size_t)s0 * 32 + coldw + 8 * t] = d0;
            partial_dw[(size_t)s1 * 32 + coldw + 8 * t] = d1;
        }

        // ---- rotate pipeline ----
        t0 = t1; t1 = t2; t2 += nwaves;
        slt0 = slt1; a0_0 = a0_1; a1_0 = a1_1;
        ir1 = ir2; orow1 = orow2; rk1 = rk2;
    }
}

// ---------------------------------------------------------------------------
// Phase 2: streaming CSR reduce, VECTORIZED. One wave per out row.
// Lane L = 8g+q reads uint4 (4 dwords = 8 cols) of entry (start + j0 + g):
// one load instruction covers 8 entries = 1 KB contiguous. Segmented reduce
// over g via shfl_xor 8/16/32; float4 stores (full 256 B per row).
// ---------------------------------------------------------------------------
__global__ __launch_bounds__(256)
void spconv_phase2(const uint4* __restrict__ partial_q,
                   const int*   __restrict__ offsets,
                   float4*      __restrict__ out4,
                   int nrows) {
    const int tid  = threadIdx.x;
    const int lane = tid & 63;
    const int g    = lane >> 3;   // entry group 0..7
    const int q    = lane & 7;    // dword-quad within entry (cols 8q..8q+7)
    const int wave = blockIdx.x * 4 + (tid >> 6);
    const int nw   = gridDim.x * 4;

    if (wave >= nrows) return;
    int cur_s = offsets[wave];
    int cur_e = offsets[wave + 1];

    for (int r = wave; r < nrows; r += nw) {
        const int start = cur_s;
        const int c     = cur_e - start;
        const int rn    = r + nw;
        if (rn < nrows) {                 // prefetch next row's extent
            cur_s = offsets[rn];
            cur_e = offsets[rn + 1];
        }

        float s0 = 0.f, s1 = 0.f, s2 = 0.f, s3 = 0.f;
        float s4 = 0.f, s5 = 0.f, s6 = 0.f, s7 = 0.f;
        for (int j0 = 0; j0 < c; j0 += 8) {
            const int j = j0 + g;
            if (j < c) {
                const uint4 v = partial_q[(size_t)(start + j) * 8 + q];
                const float2 f0 = h2f2(v.x), f1 = h2f2(v.y);
                const float2 f2 = h2f2(v.z), f3 = h2f2(v.w);
                s0 += f0.x; s1 += f0.y; s2 += f1.x; s3 += f1.y;
                s4 += f2.x; s5 += f2.y; s6 += f3.x; s7 += f3.y;
            }
        }

#pragma unroll
        for (int msk = 8; msk <= 32; msk <<= 1) {
            s0 += __shfl_xor(s0, msk); s1 += __shfl_xor(s1, msk);
            s2 += __shfl_xor(s2, msk); s3 += __shfl_xor(s3, msk);
            s4 += __shfl_xor(s4, msk); s5 += __shfl_xor(s5, msk);
            s6 += __shfl_xor(s6, msk); s7 += __shfl_xor(s7, msk);
        }

        if (g == 0) {
            out4[(size_t)r * 16 + 2 * q]     = make_float4(s0, s1, s2, s3);
            out4[(size_t)r * 16 + 2 * q + 1] = make_float4(s4, s5, s6, s7);
        }
    }
}

// ---------------------------------------------------------------------------
// Fallback (ws too small): round-2 kernel — scalar f32 atomics (known-good).
// ---------------------------------------------------------------------------
__global__ __launch_bounds__(256)
void spconv_atomic(const float* __restrict__ feats,
                   const float* __restrict__ weight,
                   const int*   __restrict__ in_map,
                   const int*   __restrict__ out_map,
                   float*       __restrict__ out,
                   int M) {
    const int k      = blockIdx.y;
    const int tid    = threadIdx.x;
    const int lane   = tid & 63;
    const int m      = lane & 15;
    const int quad   = lane >> 4;
    const int wave   = blockIdx.x * 4 + (tid >> 6);
    const int nwaves = gridDim.x * 4;

    const float* __restrict__ wk = weight + (size_t)k * (CIN * COUT);
    bf16x8 bfrag[4][2];
#pragma unroll
    for (int t = 0; t < 4; ++t)
#pragma unroll
        for (int h = 0; h < 2; ++h) {
            const int n  = 16 * t + m;
            const int c0 = 32 * h + 8 * quad;
#pragma unroll
            for (int j = 0; j < 8; ++j)
                bfrag[t][h][j] = (short)f2bf(wk[(c0 + j) * COUT + n]);
        }

    const int base   = k * M;
    const int ntiles = M >> 4;

    for (int tile = wave; tile < ntiles; tile += nwaves) {
        const int p0 = tile << 4;
        const int in_row  = in_map[base + p0 + m];
        const int out_row = out_map[base + p0 + m];

        const float* __restrict__ fr = feats + ((size_t)in_row << 6) + 8 * quad;
        const f32x4 f0 = *(const f32x4*)(fr + 0);
        const f32x4 f1 = *(const f32x4*)(fr + 4);
        const f32x4 f2 = *(const f32x4*)(fr + 32);
        const f32x4 f3 = *(const f32x4*)(fr + 36);

        bf16x8 a0, a1;
#pragma unroll
        for (int j = 0; j < 4; ++j) {
            a0[j]     = (short)f2bf(f0[j]);
            a0[j + 4] = (short)f2bf(f1[j]);
            a1[j]     = (short)f2bf(f2[j]);
            a1[j + 4] = (short)f2bf(f3[j]);
        }

        int orow[4];
#pragma unroll
        for (int r = 0; r < 4; ++r)
            orow[r] = __shfl(out_row, 4 * quad + r);

        f32x4 acc[4];
#pragma unroll
        for (int t = 0; t < 4; ++t) {
            acc[t] = {0.f, 0.f, 0.f, 0.f};
            acc[t] = __builtin_amdgcn_mfma_f32_16x16x32_bf16(a0, bfrag[t][0], acc[t], 0, 0, 0);
            acc[t] = __builtin_amdgcn_mfma_f32_16x16x32_bf16(a1, bfrag[t][1], acc[t], 0, 0, 0);
        }

#pragma unroll
        for (int t = 0; t < 4; ++t)
#pragma unroll
            for (int r = 0; r < 4; ++r)
                atomicAdd(out + (size_t)orow[r] * COUT + 16 * t + m, acc[t][r]);
    }
}

__global__ __launch_bounds__(256)
void zero_out_kernel(float4* __restrict__ out, int n4) {
    int i = blockIdx.x * 256 + threadIdx.x;
    if (i < n4) out[i] = make_float4(0.f, 0.f, 0.f, 0.f);
}

static inline size_t al256(size_t x) { return (x + 255) & ~(size_t)255; }

extern "C" void kernel_launch(void* const* d_in, const int* in_sizes, int n_in,
                              void* d_out, int out_size, void* d_ws, size_t ws_size,
                              hipStream_t stream) {
    const float* feats   = (const float*)d_in[0];
    const float* weight  = (const float*)d_in[1];
    const int*   in_map  = (const int*)d_in[2];
    const int*   out_map = (const int*)d_in[3];
    float*       out     = (float*)d_out;

    const int K     = in_sizes[1] / (CIN * COUT);   // 27
    const int M     = in_sizes[2] / K;              // 50000
    const int N     = out_size / COUT;              // 200000
    const int total = K * M;                        // 1.35M
    const int nb    = (N + 1023) >> 10;             // scan blocks (196)

    // ws layout: offsets[N+1] | cnt[N] | blocksum[nb] | blockbase[nb]
    //            | rank[total] | featsb bf16[N*CIN] | partial fp16[total*64]
    const size_t off_b  = al256((size_t)(N + 1) * 4);
    const size_t cnt_b  = al256((size_t)N * 4);
    const size_t bs_b   = al256((size_t)nb * 4);
    const size_t bb_b   = al256((size_t)nb * 4);
    const size_t rank_b = al256((size_t)total * 4);
    const size_t fb_b   = al256((size_t)N * CIN * 2);
    const size_t part_b = (size_t)total * COUT * 2;
    const size_t need   = off_b + cnt_b + bs_b + bb_b + rank_b + fb_b + part_b;

    if ((M & 15) == 0 && nb <= 256 && ws_size >= need) {
        char* p = (char*)d_ws;
        int*            offsets   = (int*)p;            p += off_b;
        int*            cnt       = (int*)p;            p += cnt_b;
        int*            blocksum  = (int*)p;            p += bs_b;
        int*            blockbase = (int*)p;            p += bb_b;
        int*            rk        = (int*)p;            p += rank_b;
        unsigned short* featsb    = (unsigned short*)p; p += fb_b;
        unsigned*       partial   = (unsigned*)p;

        const int n8 = N * CIN / 8;
        const int fused_n = (n8 > total) ? n8 : total;

        hipMemsetAsync(cnt, 0, (size_t)N * 4, stream);
        cvt_hist<<<(fused_n + 255) / 256, 256, 0, stream>>>(
            (const float4*)feats, featsb, n8, out_map, total, cnt, rk);
        scanA<<<nb, 256, 0, stream>>>(cnt, offsets, blocksum, N);
        scanB<<<1, 256, 0, stream>>>(blocksum, blockbase, nb, offsets + N);
        scanC<<<(N + 255) / 256, 256, 0, stream>>>(offsets, blockbase, N);

        dim3 g1(80, K);
        spconv_phase1<<<g1, 256, 0, stream>>>(featsb, weight, in_map, out_map,
                                              offsets, rk, partial, M);

        spconv_phase2<<<8192, 256, 0, stream>>>((const uint4*)partial, offsets,
                                                (float4*)out, N);
        return;
    }

    // Fallback: known-good scalar-atomic path.
    int n4 = out_size / 4;
    zero_out_kernel<<<(n4 + 255) / 256, 256, 0, stream>>>((float4*)out, n4);
    dim3 grid(80, K);
    spconv_atomic<<<grid, 256, 0, stream>>>(feats, weight, in_map, out_map, out, M);
}